// Round 6
// baseline (75.545 us; speedup 1.0000x reference)
//
#include <hip/hip_runtime.h>

#define DEG   32
#define NIDX  33          // DEG + self
#define F     256
#define GRID  512         // persistent blocks: 2 per CU (LDS-limited)
#define MAXR  24          // max rows per block = ceil(10000/512)=20, +margin

__global__ __launch_bounds__(256, 2) void aggregator_kernel(
    const int* __restrict__ nodes,
    const int* __restrict__ nbr,
    const float* __restrict__ feats,
    float* __restrict__ out,
    int B)
{
    const int tid  = threadIdx.x;     // 0..255 == feature column
    const int w    = tid >> 6;        // wave 0..3
    const int lane = tid & 63;
    const int bk   = blockIdx.x;

    __shared__ __align__(16) float s_feat[2][NIDX][F];  // 2 x 33 KB row buffers
    __shared__ int s_aidx[MAXR][NIDX];                  // all indices, staged once

    // rows handled by this block: r = bk + k*GRID, k = 0..n-1
    int n = 0;
    for (int r = bk; r < B; r += GRID) ++n;
    if (n == 0) return;

    // ---- prologue: stage ALL indices for this block's rows into LDS ----
    for (int e = tid; e < n * NIDX; e += 256) {
        const int k = e / NIDX;
        const int d = e - k * NIDX;
        const int r = bk + k * GRID;
        s_aidx[k][d] = (d < DEG) ? nbr[(size_t)r * DEG + d] : nodes[r];
    }
    __syncthreads();   // full drain OK here: nothing to preserve yet

    // ---- prologue DMAs: rows 0 and 1 (wave w stages d = w, w+4, ...) ----
    #pragma unroll
    for (int j = 0; j < 9; ++j) {
        const int d = w + 4 * j;
        if (d < NIDX && n > 0) {
            const float* g = feats + (size_t)s_aidx[0][d] * F + lane * 4;
            __builtin_amdgcn_global_load_lds(
                (const __attribute__((address_space(1))) void*)g,
                (__attribute__((address_space(3))) void*)&s_feat[0][d][0], 16, 0, 0);
        }
    }
    #pragma unroll
    for (int j = 0; j < 9; ++j) {
        const int d = w + 4 * j;
        if (d < NIDX && n > 1) {
            const float* g = feats + (size_t)s_aidx[1][d] * F + lane * 4;
            __builtin_amdgcn_global_load_lds(
                (const __attribute__((address_space(1))) void*)g,
                (__attribute__((address_space(3))) void*)&s_feat[1][d][0], 16, 0, 0);
        }
    }

    // ---- main loop: counted-vmcnt double-buffer (loads span barriers) ----
    for (int i = 0; i < n; ++i) {
        // 1. wait for row i's DMAs (allow row i+1's ~8 to stay in flight)
        if (i + 1 < n) asm volatile("s_waitcnt vmcnt(8)" ::: "memory");
        else           asm volatile("s_waitcnt vmcnt(0)" ::: "memory");
        // 2. all waves passed their own waits -> all of row i is in LDS
        __builtin_amdgcn_s_barrier();

        // 3a. dedup mask: lane l checks idx[l] against idx[0..l-1]
        int first = 0;
        if (lane < NIDX) {
            const int v = s_aidx[i][lane];
            first = 1;
            for (int j = 0; j < lane; ++j)
                if (s_aidx[i][j] == v) { first = 0; break; }
        }
        const unsigned long long mask = __ballot(first);
        const float den = (float)__popcll(mask);

        // 3b. accumulate column tid over the 33 staged rows (conflict-free)
        const float* buf = &s_feat[i & 1][0][0];
        float acc = 0.0f;
        #pragma unroll
        for (int d = 0; d < NIDX; ++d) {
            const float fv = buf[d * F + tid];
            const float wv = ((mask >> d) & 1ull) ? 1.0f : 0.0f;
            acc = fmaf(wv, fv, acc);
        }
        const int r = bk + i * GRID;
        out[(size_t)r * F + tid] = acc / den;

        // 4. everyone done reading buf[i&1] before overwriting it
        __builtin_amdgcn_s_barrier();

        // 5. issue row i+2 into buf[i&1] (stays in flight across barriers)
        if (i + 2 < n) {
            const int k2 = i + 2;
            #pragma unroll
            for (int j = 0; j < 9; ++j) {
                const int d = w + 4 * j;
                if (d < NIDX) {
                    const float* g = feats + (size_t)s_aidx[k2][d] * F + lane * 4;
                    __builtin_amdgcn_global_load_lds(
                        (const __attribute__((address_space(1))) void*)g,
                        (__attribute__((address_space(3))) void*)&s_feat[i & 1][d][0], 16, 0, 0);
                }
            }
        }
    }
}

extern "C" void kernel_launch(void* const* d_in, const int* in_sizes, int n_in,
                              void* d_out, int out_size, void* d_ws, size_t ws_size,
                              hipStream_t stream)
{
    const int*   nodes = (const int*)d_in[0];
    const int*   nbr   = (const int*)d_in[1];
    const float* feats = (const float*)d_in[2];
    float*       out   = (float*)d_out;

    const int B = in_sizes[0];  // 10000

    aggregator_kernel<<<GRID, 256, 0, stream>>>(nodes, nbr, feats, out, B);
}

// Round 7
// 59.536 us; speedup vs baseline: 1.2689x; 1.2689x over previous
//
#include <hip/hip_runtime.h>

#define DEG   32
#define NIDX  33
#define F     256
#define HCOLS 128          // columns per block (half of a feature row)

__global__ __launch_bounds__(256) void aggregator_kernel(
    const int* __restrict__ nodes,
    const int* __restrict__ nbr,
    const float* __restrict__ feats,
    float* __restrict__ out,
    int B)
{
    const int tid  = threadIdx.x;
    const int w    = tid >> 6;        // wave 0..3
    const int lane = tid & 63;
    const int r    = blockIdx.x >> 1; // output row
    const int h    = blockIdx.x & 1;  // column half

    __shared__ int s_idx[NIDX + 1];
    __shared__ __align__(16) float s_half[NIDX + 1][HCOLS]; // 34 x 512 B = 17 KB
    __shared__ float s_part[HCOLS];

    // ---- stage the 33 indices ----
    if (tid < NIDX)
        s_idx[tid] = (tid < DEG) ? nbr[(size_t)r * DEG + tid] : nodes[r];
    __syncthreads();

    // ---- DMA: each wave-instr stages TWO half-rows (1 KB linear LDS write):
    //      lanes 0-31 source row d, lanes 32-63 source row d+1 (per-lane
    //      global addr; wave-uniform LDS base; dest = base + lane*16).
    //      pair p -> wave (p&3): d = 2p, p = w, w+4, ..., 16 ----
    for (int p = w; p <= 16; p += 4) {
        const int d  = 2 * p;
        const int dl = d + (lane >> 5);
        const int di = (dl <= 32) ? dl : 32;   // pad slot sources row 32 (harmless)
        const float* g = feats + (size_t)s_idx[di] * F + h * HCOLS + (lane & 31) * 4;
        __builtin_amdgcn_global_load_lds(
            (const __attribute__((address_space(1))) void*)g,
            (__attribute__((address_space(3))) void*)&s_half[d][0],
            16, 0, 0);
    }

    // ---- dedup mask while DMA is in flight (ballot, no LDS weights) ----
    int first = 0;
    if (lane < NIDX) {
        const int v = s_idx[lane];
        first = 1;
        for (int j = 0; j < lane; ++j)
            if (s_idx[j] == v) { first = 0; break; }
    }
    const unsigned long long mask = __ballot(first);
    const float den = (float)__popcll(mask);

    __syncthreads();   // compiler drains vmcnt(0): all half-rows in LDS

    // ---- compute: 2 threads per column, d split 0-16 / 17-32 ----
    const int c  = tid & (HCOLS - 1);
    const int g0 = (tid >> 7) * 17;          // 0 or 17 (wave-uniform)
    const int ng = 17 - (tid >> 7);          // 17 or 16
    float acc = 0.0f;
    for (int j = 0; j < ng; ++j) {
        const int d = g0 + j;
        const float wv = ((mask >> d) & 1ull) ? 1.0f : 0.0f;
        acc = fmaf(wv, s_half[d][c], acc);
    }
    if (tid >= HCOLS) s_part[c] = acc;
    __syncthreads();
    if (tid < HCOLS)
        out[(size_t)r * F + h * HCOLS + c] = (acc + s_part[c]) / den;
}

extern "C" void kernel_launch(void* const* d_in, const int* in_sizes, int n_in,
                              void* d_out, int out_size, void* d_ws, size_t ws_size,
                              hipStream_t stream)
{
    const int*   nodes = (const int*)d_in[0];
    const int*   nbr   = (const int*)d_in[1];
    const float* feats = (const float*)d_in[2];
    float*       out   = (float*)d_out;

    const int B = in_sizes[0];  // 10000

    aggregator_kernel<<<2 * B, 256, 0, stream>>>(nodes, nbr, feats, out, B);
}

// Round 8
// 56.192 us; speedup vs baseline: 1.3444x; 1.0595x over previous
//
#include <hip/hip_runtime.h>

#define DEG 32
#define NIDX 33          // DEG + self
#define F 256
#define F4 (F / 4)       // 64 float4 per row == one wave
#define RPB 4            // rows (waves) per 256-thread block

typedef float f32x4 __attribute__((ext_vector_type(4)));

__global__ __launch_bounds__(256, 3) void aggregator_kernel(
    const int* __restrict__ nodes,
    const int* __restrict__ nbr,
    const float* __restrict__ feats,
    float* __restrict__ out,
    int B)
{
    const int tid  = threadIdx.x;
    const int wave = tid >> 6;    // 0..3  -> row within block
    const int lane = tid & 63;    // float4 column chunk
    const int b    = blockIdx.x * RPB + wave;

    __shared__ int   s_idx[RPB][NIDX];
    __shared__ float s_w[RPB][NIDX];

    // ---- stage indices: 4 rows x 33 entries, one thread each ----
    const int r = tid / NIDX;
    const int d = tid - r * NIDX;
    if (tid < RPB * NIDX) {
        const int bb = blockIdx.x * RPB + r;
        int v = 0;
        if (bb < B) v = (d < DEG) ? nbr[(size_t)bb * DEG + d] : nodes[bb];
        s_idx[r][d] = v;
    }
    __syncthreads();

    // ---- first-occurrence weights (quadratic scan, 33^2 trivial) ----
    if (tid < RPB * NIDX) {
        const int v = s_idx[r][d];
        float w = 1.0f;
        for (int j = 0; j < d; ++j) {
            if (s_idx[r][j] == v) { w = 0.0f; break; }
        }
        s_w[r][d] = w;
    }
    __syncthreads();

    if (b >= B) return;

    // ---- forced 33-deep load pipeline: asm volatile loads cannot be
    //      re-batched by the scheduler; 33 float4 results (132 VGPR) stay
    //      live until the FMA sweep -> full-depth MLP per wave ----
    f32x4 v[NIDX];
    #pragma unroll
    for (int k = 0; k < NIDX; ++k) {
        const int row = __builtin_amdgcn_readfirstlane(s_idx[wave][k]);
        const f32x4* p = (const f32x4*)(feats + (size_t)row * F) + lane;
        asm volatile("global_load_dwordx4 %0, %1, off"
                     : "=v"(v[k]) : "v"(p));
    }
    asm volatile("s_waitcnt vmcnt(0)" ::: "memory");
    __builtin_amdgcn_sched_barrier(0);   // rule #18: fence reg-only consumers

    // ---- FMA sweep; weights re-read from LDS (broadcast) to keep VGPR low ----
    float ax = 0.f, ay = 0.f, az = 0.f, aw = 0.f, den = 0.f;
    #pragma unroll
    for (int k = 0; k < NIDX; ++k) {
        const float wk = s_w[wave][k];
        den += wk;
        ax = fmaf(wk, v[k].x, ax);
        ay = fmaf(wk, v[k].y, ay);
        az = fmaf(wk, v[k].z, az);
        aw = fmaf(wk, v[k].w, aw);
    }

    const float inv = 1.0f / den;
    float4 o;
    o.x = ax * inv; o.y = ay * inv; o.z = az * inv; o.w = aw * inv;
    ((float4*)out)[(size_t)b * F4 + lane] = o;
}

extern "C" void kernel_launch(void* const* d_in, const int* in_sizes, int n_in,
                              void* d_out, int out_size, void* d_ws, size_t ws_size,
                              hipStream_t stream)
{
    const int*   nodes = (const int*)d_in[0];
    const int*   nbr   = (const int*)d_in[1];
    const float* feats = (const float*)d_in[2];
    float*       out   = (float*)d_out;

    const int B = in_sizes[0];  // 10000

    const int grid = (B + RPB - 1) / RPB;
    aggregator_kernel<<<grid, 256, 0, stream>>>(nodes, nbr, feats, out, B);
}

// Round 9
// 53.814 us; speedup vs baseline: 1.4038x; 1.0442x over previous
//
#include <hip/hip_runtime.h>

#define DEG   32
#define NIDX  33          // DEG + self
#define F     256
#define LROWS 25          // rows staged in LDS via global_load_lds
#define DROWS 8           // rows loaded direct-to-register (NIDX - LROWS)

__global__ __launch_bounds__(256) void aggregator_kernel(
    const int* __restrict__ nodes,
    const int* __restrict__ nbr,
    const float* __restrict__ feats,
    float* __restrict__ out,
    int B)
{
    const int b    = blockIdx.x;      // one output row per block (grid == B)
    const int tid  = threadIdx.x;     // 0..255 == feature column
    const int w    = tid >> 6;        // wave 0..3
    const int lane = tid & 63;

    __shared__ int   s_idx[NIDX];
    __shared__ float s_w[NIDX];
    __shared__ __align__(16) float s_feat[LROWS][F];   // 25.6 KB -> 6 blocks/CU

    // ---- stage the 33 indices ----
    if (tid < NIDX)
        s_idx[tid] = (tid < DEG) ? nbr[(size_t)b * DEG + tid] : nodes[b];
    __syncthreads();

    // ---- async DMA for rows 0..24 (zero-VGPR deep queue, ~6/wave) ----
    for (int d = w; d < LROWS; d += 4) {
        const float* g = feats + (size_t)s_idx[d] * F + lane * 4;  // 16 B/lane
        __builtin_amdgcn_global_load_lds(
            (const __attribute__((address_space(1))) void*)g,
            (__attribute__((address_space(3))) void*)&s_feat[d][0],
            16, 0, 0);
    }

    // ---- rows 25..32 direct to registers (block-coalesced 1 KB each,
    //      compiler pipelines all 8; overlaps with the DMA queue) ----
    float vr[DROWS];
    #pragma unroll
    for (int j = 0; j < DROWS; ++j)
        vr[j] = feats[(size_t)s_idx[LROWS + j] * F + tid];

    // ---- dedup weights while loads are in flight ----
    if (tid < NIDX) {
        const int v = s_idx[tid];
        float ww = 1.0f;
        for (int j = 0; j < tid; ++j)
            if (s_idx[j] == v) { ww = 0.0f; break; }
        s_w[tid] = ww;
    }
    __syncthreads();   // drains vmcnt(0)+lgkmcnt(0): all rows available

    // ---- accumulate column tid (stride-1 LDS reads: conflict-free) ----
    float den = 0.0f, acc = 0.0f;
    #pragma unroll
    for (int d = 0; d < NIDX; ++d) den += s_w[d];
    #pragma unroll
    for (int d = 0; d < LROWS; ++d)
        acc = fmaf(s_w[d], s_feat[d][tid], acc);
    #pragma unroll
    for (int j = 0; j < DROWS; ++j)
        acc = fmaf(s_w[LROWS + j], vr[j], acc);

    out[(size_t)b * F + tid] = acc / den;
}

extern "C" void kernel_launch(void* const* d_in, const int* in_sizes, int n_in,
                              void* d_out, int out_size, void* d_ws, size_t ws_size,
                              hipStream_t stream)
{
    const int*   nodes = (const int*)d_in[0];
    const int*   nbr   = (const int*)d_in[1];
    const float* feats = (const float*)d_in[2];
    float*       out   = (float*)d_out;

    const int B = in_sizes[0];  // 10000

    aggregator_kernel<<<B, 256, 0, stream>>>(nodes, nbr, feats, out, B);
}